// Round 13
// baseline (1938.674 us; speedup 1.0000x reference)
//
#include <hip/hip_runtime.h>
#include <hip/hip_cooperative_groups.h>
#include <math.h>

namespace cg = cooperative_groups;

static constexpr int NNODE = 4096;
static constexpr int HDIM  = 256;
static constexpr int DIN   = 128;
static constexpr int HEADS = 8;
static constexpr int SPLIT = 4;

using short8 = __attribute__((ext_vector_type(8))) short;
using f32x4  = __attribute__((ext_vector_type(4))) float;

__device__ inline unsigned short bfr(float x) {   // RNE fp32->bf16
    union { float f; unsigned u; } v; v.f = x;
    unsigned r = v.u + 0x7FFFu + ((v.u >> 16) & 1u);
    return (unsigned short)(r >> 16);
}
__device__ inline float bf2f(unsigned short u) {
    union { unsigned u; float f; } v; v.u = (unsigned)u << 16; return v.f;
}
__device__ inline unsigned cvt_pk_bf16(float lo, float hi) {
    unsigned r;
    asm("v_cvt_pk_bf16_f32 %0, %1, %2" : "=v"(r) : "v"(lo), "v"(hi));
    return r;
}
__device__ inline float ex2(float x) {            // bare v_exp_f32 (exp2)
    float r;
    asm("v_exp_f32 %0, %1" : "=v"(r) : "v"(x));
    return r;
}

static constexpr float QSCALE_LOG2 = 0.25503527f; // 1/sqrt(32) * log2(e)

// ---------------------------------------------------------------------------
struct Params {
    const float *x, *W1, *b1, *W2, *b2, *W3, *b3, *in_w, *in_b, *outw, *outb;
    const float *fp1w, *fp1b, *fp2w, *fp2b, *pd1w, *pd1b, *pd2w, *pd2b;
    const int* ei;
    int E;
    int* degi; int* off; int* cursor; int* csr;
    float* dinv; float* invdeg;
    unsigned short *W1t, *W2t, *W3t, *in_wb, *outwb, *wcatb;
    float* bcat;
    unsigned short* xb;
    float* bufA;                 // heads th (fp32)
    unsigned short* bufAb;       // conv hW (bf16)
    unsigned short *aggb1, *aggb2;
    float* hf;
    unsigned short* hb;
    unsigned short *qh, *kh, *vt;
    unsigned short* po;
    float* pl;
    unsigned short *ob, *hfinb;
    float* out;
};

// ---------------------------------------------------------------------------
// bf16 MFMA GEMM tile (one 64x32 block tile). A [M][K], B [Nout][K] bf16.
// EPI: 0 fp32 out, 1 bf16 out, 2 qkv (q,k head-major; v transposed).
template<int K, int EPI, bool BIAS, bool ADD>
__device__ void bgemm_tile(const unsigned short* __restrict__ A,
                           const unsigned short* __restrict__ B,
                           const float* __restrict__ bias,
                           const float* __restrict__ addsrc,
                           void* P0, void* P1, void* P2, int Nout,
                           int bx, int by, int tid) {
    const int lane = tid & 63, wave = tid >> 6;
    const int ql = lane & 15, g = lane >> 4;
    const int m0w = by * 64 + wave * 16;
    const int n0 = bx * 32;
    const unsigned short* ap = A + (size_t)(m0w + ql) * K + g * 8;
    const unsigned short* bp = B + (size_t)(n0 + ql) * K + g * 8;

    f32x4 acc[2] = {{0,0,0,0},{0,0,0,0}};
    #pragma unroll
    for (int k0 = 0; k0 < K; k0 += 32) {
        short8 a = *(const short8*)(ap + k0);
        #pragma unroll
        for (int nt = 0; nt < 2; ++nt) {
            short8 b = *(const short8*)(bp + (size_t)nt * 16 * K + k0);
            acc[nt] = __builtin_amdgcn_mfma_f32_16x16x32_bf16(a, b, acc[nt], 0, 0, 0);
        }
    }
    #pragma unroll
    for (int nt = 0; nt < 2; ++nt) {
        const int col = n0 + nt * 16 + ql;
        const float bv = BIAS ? bias[col] : 0.f;
        if (EPI == 2) {
            const int sec = col >> 8, cc = col & 255;
            const int head = cc >> 5, dh = cc & 31;
            if (sec == 2) {
                unsigned short* dst = (unsigned short*)P2
                    + ((size_t)head * 32 + dh) * NNODE + m0w + g * 4;
                uint2 pk;
                pk.x = cvt_pk_bf16(acc[nt][0] + bv, acc[nt][1] + bv);
                pk.y = cvt_pk_bf16(acc[nt][2] + bv, acc[nt][3] + bv);
                *(uint2*)dst = pk;
            } else {
                unsigned short* dst = (unsigned short*)(sec == 0 ? P0 : P1);
                const float sc = (sec == 0) ? QSCALE_LOG2 : 1.0f;
                #pragma unroll
                for (int i = 0; i < 4; ++i) {
                    int row = m0w + g * 4 + i;
                    dst[((size_t)head * NNODE + row) * 32 + dh] = bfr((acc[nt][i] + bv) * sc);
                }
            }
        } else if (EPI == 1) {
            unsigned short* Cb = (unsigned short*)P0;
            #pragma unroll
            for (int i = 0; i < 4; ++i) {
                int row = m0w + g * 4 + i;
                float v = acc[nt][i] + bv;
                if (ADD) v += addsrc[(size_t)row * Nout + col];
                Cb[(size_t)row * Nout + col] = bfr(v);
            }
        } else {
            float* Cf = (float*)P0;
            #pragma unroll
            for (int i = 0; i < 4; ++i) {
                int row = m0w + g * 4 + i;
                float v = acc[nt][i] + bv;
                if (ADD) v += addsrc[(size_t)row * Nout + col];
                Cf[(size_t)row * Nout + col] = v;
            }
        }
    }
}

template<int K, int EPI, bool BIAS, bool ADD>
__device__ void bgemm_phase(const Params& P, int nbx, int nby,
                            const unsigned short* A, const unsigned short* B,
                            const float* bias, const float* addsrc,
                            void* P0, void* P1, void* P2, int Nout,
                            int bid, int NB, int tid) {
    const int total = nbx * nby;
    for (int tb = bid; tb < total; tb += NB)
        bgemm_tile<K, EPI, BIAS, ADD>(A, B, bias, addsrc, P0, P1, P2, Nout,
                                      tb % nbx, tb / nbx, tid);
}

// ---------------------------------------------------------------------------
// wave-per-node CSR gather: lane owns 4 channels, shfl-broadcast indices.
template<int MODE>
__device__ void gather_node(const Params& P, const unsigned short* __restrict__ hW,
                            float* aggf, unsigned short* aggb,
                            const float* __restrict__ bias, int n, int lane) {
    const int start = P.off[n];
    const int cnt = P.degi[n];
    float a0 = 0.f, a1 = 0.f, a2 = 0.f, a3 = 0.f;
    for (int k0 = 0; k0 < cnt; k0 += 64) {
        int myidx = 0; float myw = 0.f;
        if (k0 + lane < cnt) {
            myidx = P.csr[start + k0 + lane];
            myw = P.dinv[myidx];
        }
        int lim = min(64, cnt - k0);
        for (int k = 0; k < lim; ++k) {
            int s = __shfl(myidx, k);
            float wgt = __shfl(myw, k);
            uint2 hv = *(const uint2*)&hW[(size_t)s * HDIM + lane * 4];
            a0 += bf2f((unsigned short)(hv.x)) * wgt;
            a1 += bf2f((unsigned short)(hv.x >> 16)) * wgt;
            a2 += bf2f((unsigned short)(hv.y)) * wgt;
            a3 += bf2f((unsigned short)(hv.y >> 16)) * wgt;
        }
    }
    float dn = P.dinv[n], idg = P.invdeg[n];
    uint2 sv = *(const uint2*)&hW[(size_t)n * HDIM + lane * 4];
    float v0 = a0 * dn + bf2f((unsigned short)(sv.x)) * idg + bias[lane*4+0];
    float v1 = a1 * dn + bf2f((unsigned short)(sv.x >> 16)) * idg + bias[lane*4+1];
    float v2 = a2 * dn + bf2f((unsigned short)(sv.y)) * idg + bias[lane*4+2];
    float v3 = a3 * dn + bf2f((unsigned short)(sv.y >> 16)) * idg + bias[lane*4+3];
    if (MODE == 0) {
        uint2 pk;
        pk.x = cvt_pk_bf16(fmaxf(v0, 0.f), fmaxf(v1, 0.f));
        pk.y = cvt_pk_bf16(fmaxf(v2, 0.f), fmaxf(v3, 0.f));
        *(uint2*)&aggb[(size_t)n * HDIM + lane * 4] = pk;
    } else {
        float4 f4 = {v0, v1, v2, v3};
        *(float4*)&aggf[(size_t)n * HDIM + lane * 4] = f4;
        uint2 pk;
        pk.x = cvt_pk_bf16(v0, v1);
        pk.y = cvt_pk_bf16(v2, v3);
        *(uint2*)&aggb[(size_t)n * HDIM + lane * 4] = pk;
    }
}

template<int MODE>
__device__ void gather_phase(const Params& P, const unsigned short* hW,
                             float* aggf, unsigned short* aggb, const float* bias,
                             int bid, int NB, int tid) {
    const int wave = tid >> 6, lane = tid & 63;
    for (int nb = bid; nb < NNODE / 4; nb += NB)
        gather_node<MODE>(P, hW, aggf, aggb, bias, nb * 4 + wave, lane);
}

// ---------------------------------------------------------------------------
// attention (identical math to the proven 46us kernel; no running max)
__device__ void softmax_16q(f32x4 st[4], float& l, unsigned short* prow, int g) {
    float ll = 0.f;
    #pragma unroll
    for (int t = 0; t < 4; ++t) {
        float p0 = ex2(st[t][0]);
        float p1 = ex2(st[t][1]);
        float p2 = ex2(st[t][2]);
        float p3 = ex2(st[t][3]);
        ll += (p0 + p1) + (p2 + p3);
        uint2 w2; w2.x = cvt_pk_bf16(p0, p1); w2.y = cvt_pk_bf16(p2, p3);
        *(uint2*)&prow[t * 16 + g * 4] = w2;
    }
    ll += __shfl_xor(ll, 16);
    ll += __shfl_xor(ll, 32);
    l += ll;
}

__device__ void attn_block(const Params& P, int bid, int tid,
                           unsigned short* Vt0, unsigned short* Vt1,
                           unsigned short* Plds /*[4][16*72]*/) {
    const int hd = bid & 7;
    const int z  = (bid >> 3) & (SPLIT - 1);
    const int qb = bid >> 5;
    const int wave = tid >> 6, lane = tid & 63;
    const int ql = lane & 15, g = lane >> 4;
    unsigned short* VtArr[2] = {Vt0, Vt1};

    const unsigned short* khh = P.kh + (size_t)hd * NNODE * 32;
    const unsigned short* vtt = P.vt + (size_t)hd * 32 * NNODE;
    const int row = qb * 64 + wave * 16 + ql;
    short8 qf = *(const short8*)(P.qh + ((size_t)hd * NNODE + row) * 32 + g * 8);

    f32x4 oa0 = {0,0,0,0}, oa1 = {0,0,0,0};
    float l = 0.f;

    const int sdh = tid >> 3, sch = (tid & 7) * 8;
    const unsigned short* vsrc = vtt + (size_t)sdh * NNODE + sch;
    const unsigned short* kbase = khh + (size_t)ql * 32 + g * 8;
    unsigned short* prow = Plds + wave * (16 * 72) + ql * 72;
    const int TPS = NNODE / 64 / SPLIT;
    const int t0 = z * TPS;

    {   // prologue: stage V^T tile t0 into buf 0
        short8 vv = *(const short8*)(vsrc + t0 * 64);
        *(short8*)&Vt0[sdh * 72 + sch] = vv;
    }
    __syncthreads();
    int cur = 0;

    for (int kt = t0; kt < t0 + TPS; ++kt) {
        short8 vv;
        const bool pref = (kt + 1 < t0 + TPS);
        if (pref) vv = *(const short8*)(vsrc + (kt + 1) * 64);

        f32x4 st[4];
        __builtin_amdgcn_s_setprio(1);
        #pragma unroll
        for (int t = 0; t < 4; ++t) {
            short8 kf = *(const short8*)(kbase + ((size_t)kt * 64 + t * 16) * 32);
            st[t] = __builtin_amdgcn_mfma_f32_16x16x32_bf16(kf, qf, (f32x4){0,0,0,0}, 0, 0, 0);
        }
        __builtin_amdgcn_s_setprio(0);

        softmax_16q(st, l, prow, g);

        if (pref) *(short8*)&VtArr[cur ^ 1][sdh * 72 + sch] = vv;

        __builtin_amdgcn_s_setprio(1);
        #pragma unroll
        for (int c = 0; c < 2; ++c) {
            short8 pf = *(const short8*)&prow[c * 32 + g * 8];
            short8 v0 = *(const short8*)&VtArr[cur][ql * 72 + c * 32 + g * 8];
            short8 v1 = *(const short8*)&VtArr[cur][(16 + ql) * 72 + c * 32 + g * 8];
            oa0 = __builtin_amdgcn_mfma_f32_16x16x32_bf16(v0, pf, oa0, 0, 0, 0);
            oa1 = __builtin_amdgcn_mfma_f32_16x16x32_bf16(v1, pf, oa1, 0, 0, 0);
        }
        __builtin_amdgcn_s_setprio(0);

        __syncthreads();
        cur ^= 1;
    }

    const size_t pidx = ((size_t)hd * NNODE + row) * SPLIT + z;
    unsigned short* pp = P.po + pidx * 32;
    uint2 r;
    r.x = cvt_pk_bf16(oa0[0], oa0[1]); r.y = cvt_pk_bf16(oa0[2], oa0[3]);
    *(uint2*)&pp[g * 4] = r;
    r.x = cvt_pk_bf16(oa1[0], oa1[1]); r.y = cvt_pk_bf16(oa1[2], oa1[3]);
    *(uint2*)&pp[16 + g * 4] = r;
    if (g == 0) P.pl[pidx] = l;
}

// ---------------------------------------------------------------------------
__device__ void heads2_node(const Params& P, int n, int lane) {
    const int half = lane >> 5;
    const int li = lane & 31;
    float4 h4 = *(const float4*)&P.bufA[(size_t)n * HDIM + half * 128 + li * 4];
    h4.x = fmaxf(h4.x, 0.f); h4.y = fmaxf(h4.y, 0.f);
    h4.z = fmaxf(h4.z, 0.f); h4.w = fmaxf(h4.w, 0.f);
    float lf[3];
    float lp[10];
    #pragma unroll
    for (int j = 0; j < 10; ++j) {
        float partial = 0.f;
        if (half == 0) {
            if (j < 3) {
                float4 wv = *(const float4*)&P.fp2w[j * 128 + li * 4];
                partial = h4.x*wv.x + h4.y*wv.y + h4.z*wv.z + h4.w*wv.w;
            }
        } else {
            float4 wv = *(const float4*)&P.pd2w[j * 128 + li * 4];
            partial = h4.x*wv.x + h4.y*wv.y + h4.z*wv.z + h4.w*wv.w;
        }
        #pragma unroll
        for (int d = 1; d < 32; d <<= 1) partial += __shfl_xor(partial, d);
        if (j < 3) lf[j] = partial;
        lp[j] = partial;
    }
    if (lane == 0) {
        float l0 = lf[0] + P.fp2b[0], l1 = lf[1] + P.fp2b[1], l2 = lf[2] + P.fp2b[2];
        float mx = fmaxf(l0, fmaxf(l1, l2));
        float e0 = __expf(l0 - mx), e1 = __expf(l1 - mx), e2 = __expf(l2 - mx);
        float inv = 1.f / (e0 + e1 + e2);
        P.out[(size_t)n * 3 + 0] = e0 * inv;
        P.out[(size_t)n * 3 + 1] = e1 * inv;
        P.out[(size_t)n * 3 + 2] = e2 * inv;
    } else if (lane == 32) {
        #pragma unroll
        for (int j = 0; j < 10; ++j)
            P.out[(size_t)NNODE * 3 + (size_t)n * 10 + j] =
                1.f / (1.f + __expf(-(lp[j] + P.pd2b[j])));
    }
}

// ---------------------------------------------------------------------------
__global__ __launch_bounds__(256, 8) void k_mega(Params P) {
    __shared__ unsigned short sVt[2][32 * 72];
    __shared__ unsigned short sPlds[4][16 * 72];
    __shared__ int sScan[256];

    cg::grid_group grid = cg::this_grid();
    const int bid = blockIdx.x, NB = gridDim.x, tid = threadIdx.x;
    const int wave = tid >> 6, lane = tid & 63;
    const int E = P.E;

    // ---- phase 0: prep (bf16 weights/x) + zero degi ----
    for (int idx = bid * 256 + tid; idx < 561152; idx += NB * 256) {
        if (idx < 32768) {                       // W1 -> W1t [256][128]
            int c = idx >> 7, k = idx & 127;
            P.W1t[idx] = bfr(P.W1[(size_t)k * 256 + c]);
        } else if (idx < 98304) {
            int j = idx - 32768; int c = j >> 8, k = j & 255;
            P.W2t[j] = bfr(P.W2[(size_t)k * 256 + c]);
        } else if (idx < 163840) {
            int j = idx - 98304; int c = j >> 8, k = j & 255;
            P.W3t[j] = bfr(P.W3[(size_t)k * 256 + c]);
        } else if (idx < 360448) {
            int j = idx - 163840;
            P.in_wb[j] = bfr(P.in_w[j]);
        } else if (idx < 425984) {
            int j = idx - 360448;
            P.outwb[j] = bfr(P.outw[j]);
        } else if (idx < 491520) {
            int j = idx - 425984;
            int row = j >> 8, k = j & 255;
            P.wcatb[j] = bfr(row < 128 ? P.fp1w[(size_t)row * 256 + k]
                                       : P.pd1w[(size_t)(row - 128) * 256 + k]);
            if (j < 256) P.bcat[j] = (j < 128) ? P.fp1b[j] : P.pd1b[j - 128];
        } else if (idx < 557056) {
            int i = (idx - 491520) * 8;
            float4 a = *(const float4*)&P.x[i];
            float4 b = *(const float4*)&P.x[i + 4];
            short8 o;
            o[0]=(short)bfr(a.x); o[1]=(short)bfr(a.y); o[2]=(short)bfr(a.z); o[3]=(short)bfr(a.w);
            o[4]=(short)bfr(b.x); o[5]=(short)bfr(b.y); o[6]=(short)bfr(b.z); o[7]=(short)bfr(b.w);
            *(short8*)&P.xb[i] = o;
        } else {
            P.degi[idx - 557056] = 0;
        }
    }
    grid.sync();

    // ---- phase 1: degree count ----
    for (int e = bid * 256 + tid; e < E; e += NB * 256)
        atomicAdd(&P.degi[P.ei[E + e]], 1);
    grid.sync();

    // ---- phase 2: scan + norms (block 0) ----
    if (bid == 0) {
        int t = tid;
        int local[16];
        int s = 0;
        #pragma unroll
        for (int i = 0; i < 16; ++i) { local[i] = P.degi[t * 16 + i]; s += local[i]; }
        sScan[t] = s;
        __syncthreads();
        #pragma unroll
        for (int d = 1; d < 256; d <<= 1) {
            int add = (t >= d) ? sScan[t - d] : 0;
            __syncthreads();
            sScan[t] += add;
            __syncthreads();
        }
        int b = sScan[t] - s;
        #pragma unroll
        for (int i = 0; i < 16; ++i) {
            int n = t * 16 + i;
            P.off[n] = b; P.cursor[n] = b; b += local[i];
            float d = (float)local[i] + 1.0f;
            P.dinv[n]   = rsqrtf(d);
            P.invdeg[n] = 1.0f / d;
        }
    }
    grid.sync();

    // ---- phase 3: CSR fill ----
    for (int e = bid * 256 + tid; e < E; e += NB * 256) {
        int d = P.ei[E + e];
        int p = atomicAdd(&P.cursor[d], 1);
        P.csr[p] = P.ei[e];
    }
    grid.sync();

    // ---- conv1 ----
    bgemm_phase<DIN, 1, false, false>(P, 8, 64, P.xb, P.W1t, nullptr, nullptr,
                                      P.bufAb, nullptr, nullptr, HDIM, bid, NB, tid);
    grid.sync();
    gather_phase<0>(P, P.bufAb, nullptr, P.aggb1, P.b1, bid, NB, tid);
    grid.sync();

    // ---- conv2 ----
    bgemm_phase<HDIM, 1, false, false>(P, 8, 64, P.aggb1, P.W2t, nullptr, nullptr,
                                       P.bufAb, nullptr, nullptr, HDIM, bid, NB, tid);
    grid.sync();
    gather_phase<0>(P, P.bufAb, nullptr, P.aggb2, P.b2, bid, NB, tid);
    grid.sync();

    // ---- conv3 ----
    bgemm_phase<HDIM, 1, false, false>(P, 8, 64, P.aggb2, P.W3t, nullptr, nullptr,
                                       P.bufAb, nullptr, nullptr, HDIM, bid, NB, tid);
    grid.sync();
    gather_phase<1>(P, P.bufAb, P.hf, P.hb, P.b3, bid, NB, tid);
    grid.sync();

    // ---- qkv GEMM (q,k head-major + V transposed) ----
    bgemm_phase<HDIM, 2, true, false>(P, 24, 64, P.hb, P.in_wb, P.in_b, nullptr,
                                      P.qh, P.kh, P.vt, 768, bid, NB, tid);
    grid.sync();

    // ---- attention ----
    for (int ab = bid; ab < HEADS * SPLIT * (NNODE / 64); ab += NB)
        attn_block(P, ab, tid, sVt[0], sVt[1], &sPlds[0][0]);
    grid.sync();

    // ---- merge ----
    for (int idx = bid * 256 + tid; idx < NNODE * HDIM; idx += NB * 256) {
        int row = idx >> 8, c = idx & 255;
        int hd = c >> 5, dh = c & 31;
        size_t b4 = ((size_t)hd * NNODE + row) * SPLIT;
        float L = 0.f, v = 0.f;
        #pragma unroll
        for (int i = 0; i < SPLIT; ++i) {
            L += P.pl[b4 + i];
            v += bf2f(P.po[(b4 + i) * 32 + dh]);
        }
        P.ob[idx] = bfr(v / L);
    }
    grid.sync();

    // ---- out-proj + residual ----
    bgemm_phase<HDIM, 1, true, true>(P, 8, 64, P.ob, P.outwb, P.outb, P.hf,
                                     P.hfinb, nullptr, nullptr, HDIM, bid, NB, tid);
    grid.sync();

    // ---- heads layer 1 ----
    bgemm_phase<HDIM, 0, true, false>(P, 8, 64, P.hfinb, P.wcatb, P.bcat, nullptr,
                                      P.bufA, nullptr, nullptr, HDIM, bid, NB, tid);
    grid.sync();

    // ---- heads layer 2 ----
    for (int nb = bid; nb < NNODE / 4; nb += NB)
        heads2_node(P, nb * 4 + wave, lane);
}

// ---------------------------------------------------------------------------
extern "C" void kernel_launch(void* const* d_in, const int* in_sizes, int n_in,
                              void* d_out, int out_size, void* d_ws, size_t ws_size,
                              hipStream_t stream) {
    Params P;
    P.x    = (const float*)d_in[0];
    P.ei   = (const int*)  d_in[1];
    P.W1   = (const float*)d_in[2];  P.b1 = (const float*)d_in[3];
    P.W2   = (const float*)d_in[4];  P.b2 = (const float*)d_in[5];
    P.W3   = (const float*)d_in[6];  P.b3 = (const float*)d_in[7];
    P.in_w = (const float*)d_in[8];  P.in_b = (const float*)d_in[9];
    P.outw = (const float*)d_in[10]; P.outb = (const float*)d_in[11];
    P.fp1w = (const float*)d_in[12]; P.fp1b = (const float*)d_in[13];
    P.fp2w = (const float*)d_in[14]; P.fp2b = (const float*)d_in[15];
    P.pd1w = (const float*)d_in[16]; P.pd1b = (const float*)d_in[17];
    P.pd2w = (const float*)d_in[18]; P.pd2b = (const float*)d_in[19];
    P.out  = (float*)d_out;
    P.E = in_sizes[1] / 2;

    char* w = (char*)d_ws;
    auto alloc = [&](size_t bytes) {
        char* p = w; w += (bytes + 255) & ~(size_t)255; return p;
    };
    P.degi   = (int*)alloc(NNODE * 4);
    P.off    = (int*)alloc(NNODE * 4);
    P.cursor = (int*)alloc(NNODE * 4);
    P.csr    = (int*)alloc((size_t)P.E * 4);
    P.dinv   = (float*)alloc(NNODE * 4);
    P.invdeg = (float*)alloc(NNODE * 4);
    P.W1t    = (unsigned short*)alloc(256 * 128 * 2);
    P.W2t    = (unsigned short*)alloc(256 * 256 * 2);
    P.W3t    = (unsigned short*)alloc(256 * 256 * 2);
    P.in_wb  = (unsigned short*)alloc(768 * 256 * 2);
    P.outwb  = (unsigned short*)alloc(256 * 256 * 2);
    P.wcatb  = (unsigned short*)alloc(256 * 256 * 2);
    P.bcat   = (float*)alloc(256 * 4);
    P.xb     = (unsigned short*)alloc((size_t)NNODE * DIN * 2);
    P.bufA   = (float*)alloc((size_t)NNODE * HDIM * 4);
    P.bufAb  = (unsigned short*)alloc((size_t)NNODE * HDIM * 2);
    P.aggb1  = (unsigned short*)alloc((size_t)NNODE * HDIM * 2);
    P.aggb2  = (unsigned short*)alloc((size_t)NNODE * HDIM * 2);
    P.hf     = (float*)alloc((size_t)NNODE * HDIM * 4);
    P.hb     = (unsigned short*)alloc((size_t)NNODE * HDIM * 2);
    P.qh     = (unsigned short*)alloc((size_t)HEADS * NNODE * 32 * 2);
    P.kh     = (unsigned short*)alloc((size_t)HEADS * NNODE * 32 * 2);
    P.vt     = (unsigned short*)alloc((size_t)HEADS * 32 * NNODE * 2);
    P.po     = (unsigned short*)alloc((size_t)HEADS * NNODE * SPLIT * 32 * 2);
    P.pl     = (float*)alloc((size_t)HEADS * NNODE * SPLIT * 4);
    P.ob     = (unsigned short*)alloc((size_t)NNODE * HDIM * 2);
    P.hfinb  = (unsigned short*)alloc((size_t)NNODE * HDIM * 2);

    // cooperative grid size: as many co-resident blocks as HW allows, <=2048
    int blocksPerCU = 0;
    static int cachedBlocks = -1;
    if (cachedBlocks < 0) {
        hipOccupancyMaxActiveBlocksPerMultiprocessor(&blocksPerCU, (const void*)k_mega, 256, 0);
        if (blocksPerCU < 1) blocksPerCU = 1;
        int nb = blocksPerCU * 256;            // 256 CUs on MI355X
        if (nb > 2048) nb = 2048;
        cachedBlocks = nb;
    }
    void* args[] = { &P };
    hipLaunchCooperativeKernel((const void*)k_mega, dim3(cachedBlocks), dim3(256),
                               args, 0, stream);
}

// Round 14
// 186.931 us; speedup vs baseline: 10.3711x; 10.3711x over previous
//
#include <hip/hip_runtime.h>
#include <math.h>

static constexpr int NNODE = 4096;
static constexpr int HDIM  = 256;
static constexpr int DIN   = 128;
static constexpr int HEADS = 8;
static constexpr int SPLIT = 4;     // attention key-split

using short8 = __attribute__((ext_vector_type(8))) short;
using f32x4  = __attribute__((ext_vector_type(4))) float;

__device__ inline unsigned short bfr(float x) {   // RNE fp32->bf16
    union { float f; unsigned u; } v; v.f = x;
    unsigned r = v.u + 0x7FFFu + ((v.u >> 16) & 1u);
    return (unsigned short)(r >> 16);
}
__device__ inline float bf2f(unsigned short u) {
    union { unsigned u; float f; } v; v.u = (unsigned)u << 16; return v.f;
}
__device__ inline unsigned cvt_pk_bf16(float lo, float hi) {
    unsigned r;
    asm("v_cvt_pk_bf16_f32 %0, %1, %2" : "=v"(r) : "v"(lo), "v"(hi));
    return r;
}
__device__ inline float ex2(float x) {            // bare v_exp_f32 (exp2)
    float r;
    asm("v_exp_f32 %0, %1" : "=v"(r) : "v"(x));
    return r;
}

// scale/sqrt(32) folded with log2(e): softmax computed in exp2 domain.
// No running max: softmax is shift-invariant and |s| is O(1) here.
static constexpr float QSCALE_LOG2 = 0.25503527f;   // 0.176776695 * 1.442695041

// ---------------------------------------------------------------------------
__global__ __launch_bounds__(256) void k_scan_norm(const int* __restrict__ degi,
        int* __restrict__ off, int* __restrict__ cursor,
        float* __restrict__ dinv, float* __restrict__ invdeg) {
    __shared__ int partial[256];
    int t = threadIdx.x;
    int local[16];
    int s = 0;
    #pragma unroll
    for (int i = 0; i < 16; ++i) { local[i] = degi[t * 16 + i]; s += local[i]; }
    partial[t] = s;
    __syncthreads();
    #pragma unroll
    for (int d = 1; d < 256; d <<= 1) {
        int add = (t >= d) ? partial[t - d] : 0;
        __syncthreads();
        partial[t] += add;
        __syncthreads();
    }
    int b = partial[t] - s;
    #pragma unroll
    for (int i = 0; i < 16; ++i) {
        int n = t * 16 + i;
        off[n] = b; cursor[n] = b; b += local[i];
        float d = (float)local[i] + 1.0f;
        dinv[n]   = rsqrtf(d);
        invdeg[n] = 1.0f / d;
    }
}

__global__ void k_fill(const int* __restrict__ ei, int* __restrict__ cursor,
                       int* __restrict__ csr, int E) {
    int e = blockIdx.x * 256 + threadIdx.x;
    if (e < E) {
        int d = ei[E + e];
        int p = atomicAdd(&cursor[d], 1);
        csr[p] = ei[e];
    }
}

// ---------------------------------------------------------------------------
// weight + x prep (bf16 convert / transpose / concat) FUSED with degree count.
// Slots: [0, 557056) prep work; [557056, 557056+E) edge-degree atomics.
__global__ __launch_bounds__(256) void k_prep(
        const float* __restrict__ W1, const float* __restrict__ W2,
        const float* __restrict__ W3, const float* __restrict__ in_w,
        const float* __restrict__ outw, const float* __restrict__ fp1w,
        const float* __restrict__ pd1w, const float* __restrict__ fp1b,
        const float* __restrict__ pd1b, const float* __restrict__ x,
        const int* __restrict__ ei, int E, int* __restrict__ degi,
        unsigned short* __restrict__ W1t, unsigned short* __restrict__ W2t,
        unsigned short* __restrict__ W3t, unsigned short* __restrict__ in_wb,
        unsigned short* __restrict__ outwb, unsigned short* __restrict__ wcatb,
        float* __restrict__ bcat, unsigned short* __restrict__ xb) {
    int idx = blockIdx.x * 256 + threadIdx.x;
    if (idx < 32768) {                       // W1 [128][256] -> W1t [256][128]
        int c = idx >> 7, k = idx & 127;
        W1t[idx] = bfr(W1[(size_t)k * 256 + c]);
    } else if (idx < 98304) {                // W2 [256][256] -> W2t
        int j = idx - 32768; int c = j >> 8, k = j & 255;
        W2t[j] = bfr(W2[(size_t)k * 256 + c]);
    } else if (idx < 163840) {
        int j = idx - 98304; int c = j >> 8, k = j & 255;
        W3t[j] = bfr(W3[(size_t)k * 256 + c]);
    } else if (idx < 360448) {               // in_w already [768][256]
        int j = idx - 163840;
        in_wb[j] = bfr(in_w[j]);
    } else if (idx < 425984) {               // outw already [256][256]
        int j = idx - 360448;
        outwb[j] = bfr(outw[j]);
    } else if (idx < 491520) {               // wcat = [fp1w; pd1w]
        int j = idx - 425984;
        int row = j >> 8, k = j & 255;
        wcatb[j] = bfr(row < 128 ? fp1w[(size_t)row * 256 + k]
                                 : pd1w[(size_t)(row - 128) * 256 + k]);
        if (j < 256) bcat[j] = (j < 128) ? fp1b[j] : pd1b[j - 128];
    } else if (idx < 557056) {               // x -> bf16, 8 elems/thread
        int i = (idx - 491520) * 8;
        float4 a = *(const float4*)&x[i];
        float4 b = *(const float4*)&x[i + 4];
        short8 o;
        o[0]=(short)bfr(a.x); o[1]=(short)bfr(a.y); o[2]=(short)bfr(a.z); o[3]=(short)bfr(a.w);
        o[4]=(short)bfr(b.x); o[5]=(short)bfr(b.y); o[6]=(short)bfr(b.z); o[7]=(short)bfr(b.w);
        *(short8*)&xb[i] = o;
    } else if (idx < 557056 + E) {           // degree count (degi pre-zeroed)
        atomicAdd(&degi[ei[E + (idx - 557056)]], 1);
    }
}

// ---------------------------------------------------------------------------
// bf16 MFMA GEMM: C[M=4096][Nout] = A_bf16 @ B_bf16^T (+bias) (+addsrc)
// EPI: 0 fp32 out, 1 bf16 out, 2 qkv (q,k head-major, q pre-scaled; v ^T).
template<int K, int EPI, bool BIAS, bool ADD>
__global__ __launch_bounds__(256) void k_bgemm(
        const unsigned short* __restrict__ A, const unsigned short* __restrict__ B,
        const float* __restrict__ bias, const float* __restrict__ addsrc,
        void* __restrict__ P0, void* __restrict__ P1, void* __restrict__ P2,
        int Nout) {
    const int lane = threadIdx.x & 63, wave = threadIdx.x >> 6;
    const int ql = lane & 15, g = lane >> 4;
    const int m0w = blockIdx.y * 64 + wave * 16;
    const int n0 = blockIdx.x * 32;
    const unsigned short* ap = A + (size_t)(m0w + ql) * K + g * 8;
    const unsigned short* bp = B + (size_t)(n0 + ql) * K + g * 8;

    f32x4 acc[2] = {{0,0,0,0},{0,0,0,0}};
    #pragma unroll
    for (int k0 = 0; k0 < K; k0 += 32) {
        short8 a = *(const short8*)(ap + k0);
        #pragma unroll
        for (int nt = 0; nt < 2; ++nt) {
            short8 b = *(const short8*)(bp + (size_t)nt * 16 * K + k0);
            acc[nt] = __builtin_amdgcn_mfma_f32_16x16x32_bf16(a, b, acc[nt], 0, 0, 0);
        }
    }
    #pragma unroll
    for (int nt = 0; nt < 2; ++nt) {
        const int col = n0 + nt * 16 + ql;
        const float bv = BIAS ? bias[col] : 0.f;
        if (EPI == 2) {
            const int sec = col >> 8, cc = col & 255;
            const int head = cc >> 5, dh = cc & 31;
            if (sec == 2) {
                unsigned short* dst = (unsigned short*)P2
                    + ((size_t)head * 32 + dh) * NNODE + m0w + g * 4;
                uint2 pk;
                pk.x = cvt_pk_bf16(acc[nt][0] + bv, acc[nt][1] + bv);
                pk.y = cvt_pk_bf16(acc[nt][2] + bv, acc[nt][3] + bv);
                *(uint2*)dst = pk;
            } else {
                unsigned short* dst = (unsigned short*)(sec == 0 ? P0 : P1);
                const float sc = (sec == 0) ? QSCALE_LOG2 : 1.0f;
                #pragma unroll
                for (int i = 0; i < 4; ++i) {
                    int row = m0w + g * 4 + i;
                    dst[((size_t)head * NNODE + row) * 32 + dh] = bfr((acc[nt][i] + bv) * sc);
                }
            }
        } else if (EPI == 1) {
            unsigned short* Cb = (unsigned short*)P0;
            #pragma unroll
            for (int i = 0; i < 4; ++i) {
                int row = m0w + g * 4 + i;
                float v = acc[nt][i] + bv;
                if (ADD) v += addsrc[(size_t)row * Nout + col];
                Cb[(size_t)row * Nout + col] = bfr(v);
            }
        } else {
            float* Cf = (float*)P0;
            #pragma unroll
            for (int i = 0; i < 4; ++i) {
                int row = m0w + g * 4 + i;
                float v = acc[nt][i] + bv;
                if (ADD) v += addsrc[(size_t)row * Nout + col];
                Cf[(size_t)row * Nout + col] = v;
            }
        }
    }
}

// ---------------------------------------------------------------------------
// out-proj GEMM with the split-K attention MERGE fused into the A-load:
// A[row][k] = (sum_z po[(hd(k)*N+row)*SPLIT+z][dh(k)]) / (sum_z pl[...z])
// hfin = A @ outw^T + outb + hf   (bf16 out)
__global__ __launch_bounds__(256) void k_bgemm_merge(
        const unsigned short* __restrict__ po, const float* __restrict__ pl,
        const unsigned short* __restrict__ B, const float* __restrict__ bias,
        const float* __restrict__ addsrc, unsigned short* __restrict__ Cb) {
    constexpr int K = HDIM;
    const int lane = threadIdx.x & 63, wave = threadIdx.x >> 6;
    const int ql = lane & 15, g = lane >> 4;
    const int m0w = blockIdx.y * 64 + wave * 16;
    const int n0 = blockIdx.x * 32;
    const int row = m0w + ql;
    const unsigned short* bp = B + (size_t)(n0 + ql) * K + g * 8;

    f32x4 acc[2] = {{0,0,0,0},{0,0,0,0}};
    #pragma unroll
    for (int k0 = 0; k0 < K; k0 += 32) {
        // ---- generate A fragment from po/pl (merge fused) ----
        const int kidx = k0 + g * 8;          // 8 consecutive, same head
        const int hd = kidx >> 5, dh0 = kidx & 31;
        const size_t b4 = ((size_t)hd * NNODE + row) * SPLIT;
        float L = pl[b4] + pl[b4 + 1] + pl[b4 + 2] + pl[b4 + 3];
        float rcpL = 1.f / L;
        short8 p0 = *(const short8*)&po[(b4 + 0) * 32 + dh0];
        short8 p1 = *(const short8*)&po[(b4 + 1) * 32 + dh0];
        short8 p2 = *(const short8*)&po[(b4 + 2) * 32 + dh0];
        short8 p3 = *(const short8*)&po[(b4 + 3) * 32 + dh0];
        float vch[8];
        #pragma unroll
        for (int i = 0; i < 8; ++i) {
            vch[i] = (bf2f((unsigned short)p0[i]) + bf2f((unsigned short)p1[i])
                    + bf2f((unsigned short)p2[i]) + bf2f((unsigned short)p3[i])) * rcpL;
        }
        short8 a;
        #pragma unroll
        for (int i = 0; i < 4; ++i) {
            unsigned pk = cvt_pk_bf16(vch[2*i], vch[2*i+1]);
            a[2*i]   = (short)(pk & 0xFFFF);
            a[2*i+1] = (short)(pk >> 16);
        }
        #pragma unroll
        for (int nt = 0; nt < 2; ++nt) {
            short8 b = *(const short8*)(bp + (size_t)nt * 16 * K + k0);
            acc[nt] = __builtin_amdgcn_mfma_f32_16x16x32_bf16(a, b, acc[nt], 0, 0, 0);
        }
    }
    #pragma unroll
    for (int nt = 0; nt < 2; ++nt) {
        const int col = n0 + nt * 16 + ql;
        const float bv = bias[col];
        #pragma unroll
        for (int i = 0; i < 4; ++i) {
            int r = m0w + g * 4 + i;
            float v = acc[nt][i] + bv + addsrc[(size_t)r * HDIM + col];
            Cb[(size_t)r * HDIM + col] = bfr(v);
        }
    }
}

// ---------------------------------------------------------------------------
// CSR gather over bf16 hW. MODE 0: bf16(relu(val)). MODE 1: fp32 + bf16.
template<int MODE>
__global__ __launch_bounds__(256) void k_gather(const unsigned short* __restrict__ hW,
        const int* __restrict__ csr, const int* __restrict__ off,
        const int* __restrict__ degi, const float* __restrict__ dinv,
        const float* __restrict__ invdeg, const float* __restrict__ bias,
        float* __restrict__ aggf, unsigned short* __restrict__ aggb) {
    const int n = blockIdx.x;
    const int c = threadIdx.x;
    const int start = off[n];
    const int cnt = degi[n];
    __shared__ int   sidx[64];
    __shared__ float swht[64];
    float a0 = 0.f, a1 = 0.f, a2 = 0.f, a3 = 0.f;
    for (int k0 = 0; k0 < cnt; k0 += 64) {
        __syncthreads();
        if (c < 64 && k0 + c < cnt) {
            int s = csr[start + k0 + c];
            sidx[c] = s;
            swht[c] = dinv[s];
        }
        __syncthreads();
        int lim = min(64, cnt - k0);
        int k = 0;
        for (; k + 4 <= lim; k += 4) {
            a0 += bf2f(hW[(size_t)sidx[k+0] * HDIM + c]) * swht[k+0];
            a1 += bf2f(hW[(size_t)sidx[k+1] * HDIM + c]) * swht[k+1];
            a2 += bf2f(hW[(size_t)sidx[k+2] * HDIM + c]) * swht[k+2];
            a3 += bf2f(hW[(size_t)sidx[k+3] * HDIM + c]) * swht[k+3];
        }
        for (; k < lim; ++k)
            a0 += bf2f(hW[(size_t)sidx[k] * HDIM + c]) * swht[k];
    }
    float acc = (a0 + a1) + (a2 + a3);
    float val = acc * dinv[n] + bf2f(hW[(size_t)n * HDIM + c]) * invdeg[n] + bias[c];
    if (MODE == 0) {
        aggb[(size_t)n * HDIM + c] = bfr(fmaxf(val, 0.f));
    } else {
        aggf[(size_t)n * HDIM + c] = val;
        aggb[(size_t)n * HDIM + c] = bfr(val);
    }
}

// ---------------------------------------------------------------------------
// attention softmax (per 16-q wave), no running max: p = exp2(s) directly.
__device__ inline void softmax_16q(f32x4 st[4], float& l,
        unsigned short* prow, int g) {
    float ll = 0.f;
    #pragma unroll
    for (int t = 0; t < 4; ++t) {
        float p0 = ex2(st[t][0]);
        float p1 = ex2(st[t][1]);
        float p2 = ex2(st[t][2]);
        float p3 = ex2(st[t][3]);
        ll += (p0 + p1) + (p2 + p3);
        uint2 w2; w2.x = cvt_pk_bf16(p0, p1); w2.y = cvt_pk_bf16(p2, p3);
        *(uint2*)&prow[t * 16 + g * 4] = w2;
    }
    ll += __shfl_xor(ll, 16);
    ll += __shfl_xor(ll, 32);
    l += ll;
}

// MFMA flash attention, split-K=4, flat grid, head = bid&7 (XCD affinity).
// One wave = 16 q rows; block = 4 waves; grid 2048 = 8 blocks/CU.
__global__ __launch_bounds__(256, 8) void k_attn_mfma(const unsigned short* __restrict__ qh,
        const unsigned short* __restrict__ kh, const unsigned short* __restrict__ vt,
        unsigned short* __restrict__ po, float* __restrict__ pl) {
    const int bid = blockIdx.x;
    const int hd = bid & 7;
    const int z  = (bid >> 3) & (SPLIT - 1);
    const int qb = bid >> 5;
    const int tid = threadIdx.x;
    const int wave = tid >> 6, lane = tid & 63;
    const int ql = lane & 15, g = lane >> 4;

    __shared__ unsigned short Vt[2][32 * 72];
    __shared__ unsigned short Plds[4][16 * 72];

    const unsigned short* khh = kh + (size_t)hd * NNODE * 32;
    const unsigned short* vtt = vt + (size_t)hd * 32 * NNODE;
    const int row = qb * 64 + wave * 16 + ql;
    short8 qf = *(const short8*)(qh + ((size_t)hd * NNODE + row) * 32 + g * 8);

    f32x4 oa0 = {0,0,0,0}, oa1 = {0,0,0,0};
    float l = 0.f;

    const int sdh = tid >> 3, sch = (tid & 7) * 8;
    const unsigned short* vsrc = vtt + (size_t)sdh * NNODE + sch;
    const unsigned short* kbase = khh + (size_t)ql * 32 + g * 8;
    unsigned short* prow = &Plds[wave][ql * 72];
    const int TPS = NNODE / 64 / SPLIT;
    const int t0 = z * TPS;

    {
        short8 vv = *(const short8*)(vsrc + t0 * 64);
        *(short8*)&Vt[0][sdh * 72 + sch] = vv;
    }
    __syncthreads();
    int cur = 0;

    for (int kt = t0; kt < t0 + TPS; ++kt) {
        short8 vv;
        const bool pref = (kt + 1 < t0 + TPS);
        if (pref) vv = *(const short8*)(vsrc + (kt + 1) * 64);

        f32x4 st[4];
        __builtin_amdgcn_s_setprio(1);
        #pragma unroll
        for (int t = 0; t < 4; ++t) {
            short8 kf = *(const short8*)(kbase + ((size_t)kt * 64 + t * 16) * 32);
            st[t] = __builtin_amdgcn_mfma_f32_16x16x32_bf16(kf, qf, (f32x4){0,0,0,0}, 0, 0, 0);
        }
        __builtin_amdgcn_s_setprio(0);

        softmax_16q(st, l, prow, g);

        if (pref) *(short8*)&Vt[cur ^ 1][sdh * 72 + sch] = vv;

        __builtin_amdgcn_s_setprio(1);
        #pragma unroll
        for (int c = 0; c < 2; ++c) {
            short8 pf = *(const short8*)&prow[c * 32 + g * 8];
            short8 v0 = *(const short8*)&Vt[cur][ql * 72 + c * 32 + g * 8];
            short8 v1 = *(const short8*)&Vt[cur][(16 + ql) * 72 + c * 32 + g * 8];
            oa0 = __builtin_amdgcn_mfma_f32_16x16x32_bf16(v0, pf, oa0, 0, 0, 0);
            oa1 = __builtin_amdgcn_mfma_f32_16x16x32_bf16(v1, pf, oa1, 0, 0, 0);
        }
        __builtin_amdgcn_s_setprio(0);

        __syncthreads();
        cur ^= 1;
    }

    const size_t pidx = ((size_t)hd * NNODE + row) * SPLIT + z;
    unsigned short* pp = po + pidx * 32;
    uint2 r;
    r.x = cvt_pk_bf16(oa0[0], oa0[1]); r.y = cvt_pk_bf16(oa0[2], oa0[3]);
    *(uint2*)&pp[g * 4] = r;
    r.x = cvt_pk_bf16(oa1[0], oa1[1]); r.y = cvt_pk_bf16(oa1[2], oa1[3]);
    *(uint2*)&pp[16 + g * 4] = r;
    if (g == 0) pl[pidx] = l;
}

// ---------------------------------------------------------------------------
// heads layer-2 epilogue: one wave per node; th = [4096][256] pre-relu fp32.
__global__ __launch_bounds__(256) void k_heads2(const float* __restrict__ th,
        const float* __restrict__ fp2w, const float* __restrict__ fp2b,
        const float* __restrict__ pd2w, const float* __restrict__ pd2b,
        float* __restrict__ out) {
    const int wave = threadIdx.x >> 6, lane = threadIdx.x & 63;
    const int n = blockIdx.x * 4 + wave;
    const int half = lane >> 5;
    const int li = lane & 31;
    float4 h4 = *(const float4*)&th[(size_t)n * HDIM + half * 128 + li * 4];
    h4.x = fmaxf(h4.x, 0.f); h4.y = fmaxf(h4.y, 0.f);
    h4.z = fmaxf(h4.z, 0.f); h4.w = fmaxf(h4.w, 0.f);
    float lf[3];
    float lp[10];
    #pragma unroll
    for (int j = 0; j < 10; ++j) {
        float partial = 0.f;
        if (half == 0) {
            if (j < 3) {
                float4 wv = *(const float4*)&fp2w[j * 128 + li * 4];
                partial = h4.x*wv.x + h4.y*wv.y + h4.z*wv.z + h4.w*wv.w;
            }
        } else {
            float4 wv = *(const float4*)&pd2w[j * 128 + li * 4];
            partial = h4.x*wv.x + h4.y*wv.y + h4.z*wv.z + h4.w*wv.w;
        }
        #pragma unroll
        for (int d = 1; d < 32; d <<= 1) partial += __shfl_xor(partial, d);
        if (j < 3) lf[j] = partial;
        lp[j] = partial;
    }
    if (lane == 0) {
        float l0 = lf[0] + fp2b[0], l1 = lf[1] + fp2b[1], l2 = lf[2] + fp2b[2];
        float mx = fmaxf(l0, fmaxf(l1, l2));
        float e0 = __expf(l0 - mx), e1 = __expf(l1 - mx), e2 = __expf(l2 - mx);
        float inv = 1.f / (e0 + e1 + e2);
        out[(size_t)n * 3 + 0] = e0 * inv;
        out[(size_t)n * 3 + 1] = e1 * inv;
        out[(size_t)n * 3 + 2] = e2 * inv;
    } else if (lane == 32) {
        #pragma unroll
        for (int j = 0; j < 10; ++j)
            out[(size_t)NNODE * 3 + (size_t)n * 10 + j] =
                1.f / (1.f + __expf(-(lp[j] + pd2b[j])));
    }
}

// ---------------------------------------------------------------------------
extern "C" void kernel_launch(void* const* d_in, const int* in_sizes, int n_in,
                              void* d_out, int out_size, void* d_ws, size_t ws_size,
                              hipStream_t stream) {
    const float* x    = (const float*)d_in[0];
    const int*   ei   = (const int*)  d_in[1];
    const float* W1   = (const float*)d_in[2];
    const float* b1   = (const float*)d_in[3];
    const float* W2   = (const float*)d_in[4];
    const float* b2   = (const float*)d_in[5];
    const float* W3   = (const float*)d_in[6];
    const float* b3   = (const float*)d_in[7];
    const float* in_w = (const float*)d_in[8];
    const float* in_b = (const float*)d_in[9];
    const float* outw = (const float*)d_in[10];
    const float* outb = (const float*)d_in[11];
    const float* fp1w = (const float*)d_in[12];
    const float* fp1b = (const float*)d_in[13];
    const float* fp2w = (const float*)d_in[14];
    const float* fp2b = (const float*)d_in[15];
    const float* pd1w = (const float*)d_in[16];
    const float* pd1b = (const float*)d_in[17];
    const float* pd2w = (const float*)d_in[18];
    const float* pd2b = (const float*)d_in[19];
    float* out = (float*)d_out;

    const int E = in_sizes[1] / 2;

    char* w = (char*)d_ws;
    auto alloc = [&](size_t bytes) {
        char* p = w; w += (bytes + 255) & ~(size_t)255; return p;
    };
    int*   degi   = (int*)alloc(NNODE * 4);
    int*   off    = (int*)alloc(NNODE * 4);
    int*   cursor = (int*)alloc(NNODE * 4);
    int*   csr    = (int*)alloc((size_t)E * 4);
    float* dinv   = (float*)alloc(NNODE * 4);
    float* invdeg = (float*)alloc(NNODE * 4);
    unsigned short* W1t   = (unsigned short*)alloc(256 * 128 * 2);
    unsigned short* W2t   = (unsigned short*)alloc(256 * 256 * 2);
    unsigned short* W3t   = (unsigned short*)alloc(256 * 256 * 2);
    unsigned short* in_wb = (unsigned short*)alloc(768 * 256 * 2);
    unsigned short* outwb = (unsigned short*)alloc(256 * 256 * 2);
    unsigned short* wcatb = (unsigned short*)alloc(256 * 256 * 2);
    float* bcat  = (float*)alloc(256 * 4);
    unsigned short* xb    = (unsigned short*)alloc((size_t)NNODE * DIN * 2);
    float* bufA  = (float*)alloc((size_t)NNODE * HDIM * 4);
    unsigned short* bufAb = (unsigned short*)alloc((size_t)NNODE * HDIM * 2);
    unsigned short* aggb1 = (unsigned short*)alloc((size_t)NNODE * HDIM * 2);
    unsigned short* aggb2 = (unsigned short*)alloc((size_t)NNODE * HDIM * 2);
    float* hf    = (float*)alloc((size_t)NNODE * HDIM * 4);
    unsigned short* hb    = (unsigned short*)alloc((size_t)NNODE * HDIM * 2);
    unsigned short* qh    = (unsigned short*)alloc((size_t)HEADS * NNODE * 32 * 2);
    unsigned short* kh    = (unsigned short*)alloc((size_t)HEADS * NNODE * 32 * 2);
    unsigned short* vt    = (unsigned short*)alloc((size_t)HEADS * 32 * NNODE * 2);
    unsigned short* po    = (unsigned short*)alloc((size_t)HEADS * NNODE * SPLIT * 32 * 2);
    float* pl    = (float*)alloc((size_t)HEADS * NNODE * SPLIT * 4);
    unsigned short* hfinb = (unsigned short*)alloc((size_t)NNODE * HDIM * 2);

    // CSR + prep (deg fused into prep; degi zeroed by async memset)
    hipMemsetAsync(degi, 0, NNODE * sizeof(int), stream);
    const int prep_slots = 557056 + E;
    k_prep<<<(prep_slots + 255) / 256, 256, 0, stream>>>(
        W1, W2, W3, in_w, outw, fp1w, pd1w, fp1b, pd1b, x, ei, E, degi,
        W1t, W2t, W3t, in_wb, outwb, wcatb, bcat, xb);
    k_scan_norm<<<1, 256, 0, stream>>>(degi, off, cursor, dinv, invdeg);
    k_fill<<<(E + 255) / 256, 256, 0, stream>>>(ei, cursor, csr, E);

    dim3 g256(HDIM / 32, NNODE / 64);   // (8,64)
    dim3 g768(768 / 32, NNODE / 64);    // (24,64)

    // conv1
    k_bgemm<DIN, 1, false, false><<<g256, 256, 0, stream>>>(xb, W1t, nullptr, nullptr, bufAb, nullptr, nullptr, HDIM);
    k_gather<0><<<NNODE, 256, 0, stream>>>(bufAb, csr, off, degi, dinv, invdeg, b1, nullptr, aggb1);
    // conv2
    k_bgemm<HDIM, 1, false, false><<<g256, 256, 0, stream>>>(aggb1, W2t, nullptr, nullptr, bufAb, nullptr, nullptr, HDIM);
    k_gather<0><<<NNODE, 256, 0, stream>>>(bufAb, csr, off, degi, dinv, invdeg, b2, nullptr, aggb2);
    // conv3
    k_bgemm<HDIM, 1, false, false><<<g256, 256, 0, stream>>>(aggb2, W3t, nullptr, nullptr, bufAb, nullptr, nullptr, HDIM);
    k_gather<1><<<NNODE, 256, 0, stream>>>(bufAb, csr, off, degi, dinv, invdeg, b3, hf, hb);

    // MHA: qkv GEMM (q,k head-major; V transposed), attention, fused merge+out-proj
    k_bgemm<HDIM, 2, true, false><<<g768, 256, 0, stream>>>(hb, in_wb, in_b, nullptr, qh, kh, vt, 768);
    k_attn_mfma<<<HEADS * SPLIT * (NNODE / 64), 256, 0, stream>>>(qh, kh, vt, po, pl);
    k_bgemm_merge<<<g256, 256, 0, stream>>>(po, pl, outwb, outb, hf, hfinb);

    // MLP heads
    k_bgemm<HDIM, 0, true, false><<<g256, 256, 0, stream>>>(hfinb, wcatb, bcat, nullptr, bufA, nullptr, nullptr, HDIM);
    k_heads2<<<NNODE / 4, 256, 0, stream>>>(bufA, fp2w, fp2b, pd2w, pd2b, out);
}

// Round 15
// 185.907 us; speedup vs baseline: 10.4282x; 1.0055x over previous
//
#include <hip/hip_runtime.h>
#include <math.h>

static constexpr int NNODE = 4096;
static constexpr int HDIM  = 256;
static constexpr int DIN   = 128;
static constexpr int HEADS = 8;
static constexpr int SPLIT = 4;     // attention key-split

using short8 = __attribute__((ext_vector_type(8))) short;
using f32x4  = __attribute__((ext_vector_type(4))) float;

__device__ inline unsigned short bfr(float x) {   // RNE fp32->bf16
    union { float f; unsigned u; } v; v.f = x;
    unsigned r = v.u + 0x7FFFu + ((v.u >> 16) & 1u);
    return (unsigned short)(r >> 16);
}
__device__ inline float bf2f(unsigned short u) {
    union { unsigned u; float f; } v; v.u = (unsigned)u << 16; return v.f;
}
__device__ inline unsigned cvt_pk_bf16(float lo, float hi) {
    unsigned r;
    asm("v_cvt_pk_bf16_f32 %0, %1, %2" : "=v"(r) : "v"(lo), "v"(hi));
    return r;
}
__device__ inline float ex2(float x) {            // bare v_exp_f32 (exp2)
    float r;
    asm("v_exp_f32 %0, %1" : "=v"(r) : "v"(x));
    return r;
}

// scale/sqrt(32) folded with log2(e): softmax computed in exp2 domain.
// No running max: softmax is shift-invariant and |s| is O(1) here.
static constexpr float QSCALE_LOG2 = 0.25503527f;   // 0.176776695 * 1.442695041

// ---------------------------------------------------------------------------
__global__ __launch_bounds__(256) void k_scan_norm(const int* __restrict__ degi,
        int* __restrict__ off, int* __restrict__ cursor,
        float* __restrict__ dinv, float* __restrict__ invdeg) {
    __shared__ int partial[256];
    int t = threadIdx.x;
    int local[16];
    int s = 0;
    #pragma unroll
    for (int i = 0; i < 16; ++i) { local[i] = degi[t * 16 + i]; s += local[i]; }
    partial[t] = s;
    __syncthreads();
    #pragma unroll
    for (int d = 1; d < 256; d <<= 1) {
        int add = (t >= d) ? partial[t - d] : 0;
        __syncthreads();
        partial[t] += add;
        __syncthreads();
    }
    int b = partial[t] - s;
    #pragma unroll
    for (int i = 0; i < 16; ++i) {
        int n = t * 16 + i;
        off[n] = b; cursor[n] = b; b += local[i];
        float d = (float)local[i] + 1.0f;
        dinv[n]   = rsqrtf(d);
        invdeg[n] = 1.0f / d;
    }
}

__global__ void k_fill(const int* __restrict__ ei, int* __restrict__ cursor,
                       int* __restrict__ csr, int E) {
    int e = blockIdx.x * 256 + threadIdx.x;
    if (e < E) {
        int d = ei[E + e];
        int p = atomicAdd(&cursor[d], 1);
        csr[p] = ei[e];
    }
}

// ---------------------------------------------------------------------------
// weight + x prep (bf16 convert / transpose / concat) FUSED with degree count.
__global__ __launch_bounds__(256) void k_prep(
        const float* __restrict__ W1, const float* __restrict__ W2,
        const float* __restrict__ W3, const float* __restrict__ in_w,
        const float* __restrict__ outw, const float* __restrict__ fp1w,
        const float* __restrict__ pd1w, const float* __restrict__ fp1b,
        const float* __restrict__ pd1b, const float* __restrict__ x,
        const int* __restrict__ ei, int E, int* __restrict__ degi,
        unsigned short* __restrict__ W1t, unsigned short* __restrict__ W2t,
        unsigned short* __restrict__ W3t, unsigned short* __restrict__ in_wb,
        unsigned short* __restrict__ outwb, unsigned short* __restrict__ wcatb,
        float* __restrict__ bcat, unsigned short* __restrict__ xb) {
    int idx = blockIdx.x * 256 + threadIdx.x;
    if (idx < 32768) {                       // W1 [128][256] -> W1t [256][128]
        int c = idx >> 7, k = idx & 127;
        W1t[idx] = bfr(W1[(size_t)k * 256 + c]);
    } else if (idx < 98304) {                // W2 [256][256] -> W2t
        int j = idx - 32768; int c = j >> 8, k = j & 255;
        W2t[j] = bfr(W2[(size_t)k * 256 + c]);
    } else if (idx < 163840) {
        int j = idx - 98304; int c = j >> 8, k = j & 255;
        W3t[j] = bfr(W3[(size_t)k * 256 + c]);
    } else if (idx < 360448) {               // in_w already [768][256]
        int j = idx - 163840;
        in_wb[j] = bfr(in_w[j]);
    } else if (idx < 425984) {               // outw already [256][256]
        int j = idx - 360448;
        outwb[j] = bfr(outw[j]);
    } else if (idx < 491520) {               // wcat = [fp1w; pd1w]
        int j = idx - 425984;
        int row = j >> 8, k = j & 255;
        wcatb[j] = bfr(row < 128 ? fp1w[(size_t)row * 256 + k]
                                 : pd1w[(size_t)(row - 128) * 256 + k]);
        if (j < 256) bcat[j] = (j < 128) ? fp1b[j] : pd1b[j - 128];
    } else if (idx < 557056) {               // x -> bf16, 8 elems/thread
        int i = (idx - 491520) * 8;
        float4 a = *(const float4*)&x[i];
        float4 b = *(const float4*)&x[i + 4];
        short8 o;
        o[0]=(short)bfr(a.x); o[1]=(short)bfr(a.y); o[2]=(short)bfr(a.z); o[3]=(short)bfr(a.w);
        o[4]=(short)bfr(b.x); o[5]=(short)bfr(b.y); o[6]=(short)bfr(b.z); o[7]=(short)bfr(b.w);
        *(short8*)&xb[i] = o;
    } else if (idx < 557056 + E) {           // degree count (degi pre-zeroed)
        atomicAdd(&degi[ei[E + (idx - 557056)]], 1);
    }
}

// ---------------------------------------------------------------------------
// bf16 MFMA GEMM: C[M=4096][Nout] = A_bf16 @ B_bf16^T (+bias) (+addsrc)
// EPI: 0 fp32 out, 1 bf16 out, 2 qkv (q,k head-major, q pre-scaled; v ^T).
template<int K, int EPI, bool BIAS, bool ADD>
__global__ __launch_bounds__(256) void k_bgemm(
        const unsigned short* __restrict__ A, const unsigned short* __restrict__ B,
        const float* __restrict__ bias, const float* __restrict__ addsrc,
        void* __restrict__ P0, void* __restrict__ P1, void* __restrict__ P2,
        int Nout) {
    const int lane = threadIdx.x & 63, wave = threadIdx.x >> 6;
    const int ql = lane & 15, g = lane >> 4;
    const int m0w = blockIdx.y * 64 + wave * 16;
    const int n0 = blockIdx.x * 32;
    const unsigned short* ap = A + (size_t)(m0w + ql) * K + g * 8;
    const unsigned short* bp = B + (size_t)(n0 + ql) * K + g * 8;

    f32x4 acc[2] = {{0,0,0,0},{0,0,0,0}};
    #pragma unroll
    for (int k0 = 0; k0 < K; k0 += 32) {
        short8 a = *(const short8*)(ap + k0);
        #pragma unroll
        for (int nt = 0; nt < 2; ++nt) {
            short8 b = *(const short8*)(bp + (size_t)nt * 16 * K + k0);
            acc[nt] = __builtin_amdgcn_mfma_f32_16x16x32_bf16(a, b, acc[nt], 0, 0, 0);
        }
    }
    #pragma unroll
    for (int nt = 0; nt < 2; ++nt) {
        const int col = n0 + nt * 16 + ql;
        const float bv = BIAS ? bias[col] : 0.f;
        if (EPI == 2) {
            const int sec = col >> 8, cc = col & 255;
            const int head = cc >> 5, dh = cc & 31;
            if (sec == 2) {
                unsigned short* dst = (unsigned short*)P2
                    + ((size_t)head * 32 + dh) * NNODE + m0w + g * 4;
                uint2 pk;
                pk.x = cvt_pk_bf16(acc[nt][0] + bv, acc[nt][1] + bv);
                pk.y = cvt_pk_bf16(acc[nt][2] + bv, acc[nt][3] + bv);
                *(uint2*)dst = pk;
            } else {
                unsigned short* dst = (unsigned short*)(sec == 0 ? P0 : P1);
                const float sc = (sec == 0) ? QSCALE_LOG2 : 1.0f;
                #pragma unroll
                for (int i = 0; i < 4; ++i) {
                    int row = m0w + g * 4 + i;
                    dst[((size_t)head * NNODE + row) * 32 + dh] = bfr((acc[nt][i] + bv) * sc);
                }
            }
        } else if (EPI == 1) {
            unsigned short* Cb = (unsigned short*)P0;
            #pragma unroll
            for (int i = 0; i < 4; ++i) {
                int row = m0w + g * 4 + i;
                float v = acc[nt][i] + bv;
                if (ADD) v += addsrc[(size_t)row * Nout + col];
                Cb[(size_t)row * Nout + col] = bfr(v);
            }
        } else {
            float* Cf = (float*)P0;
            #pragma unroll
            for (int i = 0; i < 4; ++i) {
                int row = m0w + g * 4 + i;
                float v = acc[nt][i] + bv;
                if (ADD) v += addsrc[(size_t)row * Nout + col];
                Cf[(size_t)row * Nout + col] = v;
            }
        }
    }
}

// ---------------------------------------------------------------------------
// out-proj GEMM with the split-K attention MERGE fused into the A-load.
__global__ __launch_bounds__(256) void k_bgemm_merge(
        const unsigned short* __restrict__ po, const float* __restrict__ pl,
        const unsigned short* __restrict__ B, const float* __restrict__ bias,
        const float* __restrict__ addsrc, unsigned short* __restrict__ Cb) {
    constexpr int K = HDIM;
    const int lane = threadIdx.x & 63, wave = threadIdx.x >> 6;
    const int ql = lane & 15, g = lane >> 4;
    const int m0w = blockIdx.y * 64 + wave * 16;
    const int n0 = blockIdx.x * 32;
    const int row = m0w + ql;
    const unsigned short* bp = B + (size_t)(n0 + ql) * K + g * 8;

    f32x4 acc[2] = {{0,0,0,0},{0,0,0,0}};
    #pragma unroll
    for (int k0 = 0; k0 < K; k0 += 32) {
        const int kidx = k0 + g * 8;          // 8 consecutive, same head
        const int hd = kidx >> 5, dh0 = kidx & 31;
        const size_t b4 = ((size_t)hd * NNODE + row) * SPLIT;
        float L = pl[b4] + pl[b4 + 1] + pl[b4 + 2] + pl[b4 + 3];
        float rcpL = 1.f / L;
        short8 p0 = *(const short8*)&po[(b4 + 0) * 32 + dh0];
        short8 p1 = *(const short8*)&po[(b4 + 1) * 32 + dh0];
        short8 p2 = *(const short8*)&po[(b4 + 2) * 32 + dh0];
        short8 p3 = *(const short8*)&po[(b4 + 3) * 32 + dh0];
        float vch[8];
        #pragma unroll
        for (int i = 0; i < 8; ++i) {
            vch[i] = (bf2f((unsigned short)p0[i]) + bf2f((unsigned short)p1[i])
                    + bf2f((unsigned short)p2[i]) + bf2f((unsigned short)p3[i])) * rcpL;
        }
        short8 a;
        #pragma unroll
        for (int i = 0; i < 4; ++i) {
            unsigned pk = cvt_pk_bf16(vch[2*i], vch[2*i+1]);
            a[2*i]   = (short)(pk & 0xFFFF);
            a[2*i+1] = (short)(pk >> 16);
        }
        #pragma unroll
        for (int nt = 0; nt < 2; ++nt) {
            short8 b = *(const short8*)(bp + (size_t)nt * 16 * K + k0);
            acc[nt] = __builtin_amdgcn_mfma_f32_16x16x32_bf16(a, b, acc[nt], 0, 0, 0);
        }
    }
    #pragma unroll
    for (int nt = 0; nt < 2; ++nt) {
        const int col = n0 + nt * 16 + ql;
        const float bv = bias[col];
        #pragma unroll
        for (int i = 0; i < 4; ++i) {
            int r = m0w + g * 4 + i;
            float v = acc[nt][i] + bv + addsrc[(size_t)r * HDIM + col];
            Cb[(size_t)r * HDIM + col] = bfr(v);
        }
    }
}

// ---------------------------------------------------------------------------
// CSR gather over bf16 hW. MODE 0: bf16(relu(val)). MODE 1: fp32 + bf16.
template<int MODE>
__global__ __launch_bounds__(256) void k_gather(const unsigned short* __restrict__ hW,
        const int* __restrict__ csr, const int* __restrict__ off,
        const int* __restrict__ degi, const float* __restrict__ dinv,
        const float* __restrict__ invdeg, const float* __restrict__ bias,
        float* __restrict__ aggf, unsigned short* __restrict__ aggb) {
    const int n = blockIdx.x;
    const int c = threadIdx.x;
    const int start = off[n];
    const int cnt = degi[n];
    __shared__ int   sidx[64];
    __shared__ float swht[64];
    float a0 = 0.f, a1 = 0.f, a2 = 0.f, a3 = 0.f;
    for (int k0 = 0; k0 < cnt; k0 += 64) {
        __syncthreads();
        if (c < 64 && k0 + c < cnt) {
            int s = csr[start + k0 + c];
            sidx[c] = s;
            swht[c] = dinv[s];
        }
        __syncthreads();
        int lim = min(64, cnt - k0);
        int k = 0;
        for (; k + 4 <= lim; k += 4) {
            a0 += bf2f(hW[(size_t)sidx[k+0] * HDIM + c]) * swht[k+0];
            a1 += bf2f(hW[(size_t)sidx[k+1] * HDIM + c]) * swht[k+1];
            a2 += bf2f(hW[(size_t)sidx[k+2] * HDIM + c]) * swht[k+2];
            a3 += bf2f(hW[(size_t)sidx[k+3] * HDIM + c]) * swht[k+3];
        }
        for (; k < lim; ++k)
            a0 += bf2f(hW[(size_t)sidx[k] * HDIM + c]) * swht[k];
    }
    float acc = (a0 + a1) + (a2 + a3);
    float val = acc * dinv[n] + bf2f(hW[(size_t)n * HDIM + c]) * invdeg[n] + bias[c];
    if (MODE == 0) {
        aggb[(size_t)n * HDIM + c] = bfr(fmaxf(val, 0.f));
    } else {
        aggf[(size_t)n * HDIM + c] = val;
        aggb[(size_t)n * HDIM + c] = bfr(val);
    }
}

// ---------------------------------------------------------------------------
// attention softmax (per 16-q wave), no running max: p = exp2(s) directly.
__device__ inline void softmax_16q(f32x4 st[4], float& l,
        unsigned short* prow, int g) {
    float ll = 0.f;
    #pragma unroll
    for (int t = 0; t < 4; ++t) {
        float p0 = ex2(st[t][0]);
        float p1 = ex2(st[t][1]);
        float p2 = ex2(st[t][2]);
        float p3 = ex2(st[t][3]);
        ll += (p0 + p1) + (p2 + p3);
        uint2 w2; w2.x = cvt_pk_bf16(p0, p1); w2.y = cvt_pk_bf16(p2, p3);
        *(uint2*)&prow[t * 16 + g * 4] = w2;
    }
    ll += __shfl_xor(ll, 16);
    ll += __shfl_xor(ll, 32);
    l += ll;
}

// MFMA flash attention, split-K=4, flat grid, head = bid&7 (XCD affinity).
// NEW: K tile ALSO staged through LDS (double-buffered alongside V^T) —
// per-wave K fragments become deterministic ds_read_b128 instead of 4
// vmcnt-exposed global loads. VMEM inst per wave-tile: 5 -> 2.
__global__ __launch_bounds__(256, 4) void k_attn_mfma(const unsigned short* __restrict__ qh,
        const unsigned short* __restrict__ kh, const unsigned short* __restrict__ vt,
        unsigned short* __restrict__ po, float* __restrict__ pl) {
    const int bid = blockIdx.x;
    const int hd = bid & 7;
    const int z  = (bid >> 3) & (SPLIT - 1);
    const int qb = bid >> 5;
    const int tid = threadIdx.x;
    const int wave = tid >> 6, lane = tid & 63;
    const int ql = lane & 15, g = lane >> 4;

    __shared__ unsigned short Klds[2][64 * 40];   // [key][dh] pad 40 (10.2 KB)
    __shared__ unsigned short Vt[2][32 * 72];     // [dh][key] pad 72 (9.2 KB)
    __shared__ unsigned short Plds[4][16 * 72];   // per wave [q][key] (9.2 KB)

    const unsigned short* khh = kh + (size_t)hd * NNODE * 32;
    const unsigned short* vtt = vt + (size_t)hd * 32 * NNODE;
    const int row = qb * 64 + wave * 16 + ql;
    short8 qf = *(const short8*)(qh + ((size_t)hd * NNODE + row) * 32 + g * 8);

    f32x4 oa0 = {0,0,0,0}, oa1 = {0,0,0,0};
    float l = 0.f;

    // staging maps: K: thread -> key=tid>>2, dh chunk=(tid&3)*8
    //               V: thread -> dh=tid>>3,  key chunk=(tid&7)*8
    const int skey = tid >> 2, skc = (tid & 3) * 8;
    const int sdh = tid >> 3, sch = (tid & 7) * 8;
    const unsigned short* ksrc = khh + (size_t)skey * 32 + skc;
    const unsigned short* vsrc = vtt + (size_t)sdh * NNODE + sch;
    unsigned short* prow = &Plds[wave][ql * 72];
    const int TPS = NNODE / 64 / SPLIT;
    const int t0 = z * TPS;

    {   // prologue: stage K and V tiles for t0 into buf 0
        short8 kv = *(const short8*)(ksrc + (size_t)t0 * 64 * 32);
        short8 vv = *(const short8*)(vsrc + t0 * 64);
        *(short8*)&Klds[0][skey * 40 + skc] = kv;
        *(short8*)&Vt[0][sdh * 72 + sch] = vv;
    }
    __syncthreads();
    int cur = 0;

    for (int kt = t0; kt < t0 + TPS; ++kt) {
        // issue next K+V tile loads early (writes land after softmax)
        short8 kv, vv;
        const bool pref = (kt + 1 < t0 + TPS);
        if (pref) {
            kv = *(const short8*)(ksrc + (size_t)(kt + 1) * 64 * 32);
            vv = *(const short8*)(vsrc + (kt + 1) * 64);
        }

        // S^T[64k x 16q]: K fragments from LDS (deterministic latency)
        f32x4 st[4];
        __builtin_amdgcn_s_setprio(1);
        #pragma unroll
        for (int t = 0; t < 4; ++t) {
            short8 kf = *(const short8*)&Klds[cur][(t * 16 + ql) * 40 + g * 8];
            st[t] = __builtin_amdgcn_mfma_f32_16x16x32_bf16(kf, qf, (f32x4){0,0,0,0}, 0, 0, 0);
        }
        __builtin_amdgcn_s_setprio(0);

        softmax_16q(st, l, prow, g);

        // stage next K+V tiles (vmcnt wait hidden under QK+softmax above)
        if (pref) {
            *(short8*)&Klds[cur ^ 1][skey * 40 + skc] = kv;
            *(short8*)&Vt[cur ^ 1][sdh * 72 + sch] = vv;
        }

        // O^T += V^T · P^T from LDS
        __builtin_amdgcn_s_setprio(1);
        #pragma unroll
        for (int c = 0; c < 2; ++c) {
            short8 pf = *(const short8*)&prow[c * 32 + g * 8];
            short8 v0 = *(const short8*)&Vt[cur][ql * 72 + c * 32 + g * 8];
            short8 v1 = *(const short8*)&Vt[cur][(16 + ql) * 72 + c * 32 + g * 8];
            oa0 = __builtin_amdgcn_mfma_f32_16x16x32_bf16(v0, pf, oa0, 0, 0, 0);
            oa1 = __builtin_amdgcn_mfma_f32_16x16x32_bf16(v1, pf, oa1, 0, 0, 0);
        }
        __builtin_amdgcn_s_setprio(0);

        __syncthreads();   // next tiles staged; everyone done with buf cur
        cur ^= 1;
    }

    const size_t pidx = ((size_t)hd * NNODE + row) * SPLIT + z;
    unsigned short* pp = po + pidx * 32;
    uint2 r;
    r.x = cvt_pk_bf16(oa0[0], oa0[1]); r.y = cvt_pk_bf16(oa0[2], oa0[3]);
    *(uint2*)&pp[g * 4] = r;
    r.x = cvt_pk_bf16(oa1[0], oa1[1]); r.y = cvt_pk_bf16(oa1[2], oa1[3]);
    *(uint2*)&pp[16 + g * 4] = r;
    if (g == 0) pl[pidx] = l;
}

// ---------------------------------------------------------------------------
// heads layer-2 epilogue: one wave per node; th = [4096][256] pre-relu fp32.
__global__ __launch_bounds__(256) void k_heads2(const float* __restrict__ th,
        const float* __restrict__ fp2w, const float* __restrict__ fp2b,
        const float* __restrict__ pd2w, const float* __restrict__ pd2b,
        float* __restrict__ out) {
    const int wave = threadIdx.x >> 6, lane = threadIdx.x & 63;
    const int n = blockIdx.x * 4 + wave;
    const int half = lane >> 5;
    const int li = lane & 31;
    float4 h4 = *(const float4*)&th[(size_t)n * HDIM + half * 128 + li * 4];
    h4.x = fmaxf(h4.x, 0.f); h4.y = fmaxf(h4.y, 0.f);
    h4.z = fmaxf(h4.z, 0.f); h4.w = fmaxf(h4.w, 0.f);
    float lf[3];
    float lp[10];
    #pragma unroll
    for (int j = 0; j < 10; ++j) {
        float partial = 0.f;
        if (half == 0) {
            if (j < 3) {
                float4 wv = *(const float4*)&fp2w[j * 128 + li * 4];
                partial = h4.x*wv.x + h4.y*wv.y + h4.z*wv.z + h4.w*wv.w;
            }
        } else {
            float4 wv = *(const float4*)&pd2w[j * 128 + li * 4];
            partial = h4.x*wv.x + h4.y*wv.y + h4.z*wv.z + h4.w*wv.w;
        }
        #pragma unroll
        for (int d = 1; d < 32; d <<= 1) partial += __shfl_xor(partial, d);
        if (j < 3) lf[j] = partial;
        lp[j] = partial;
    }
    if (lane == 0) {
        float l0 = lf[0] + fp2b[0], l1 = lf[1] + fp2b[1], l2 = lf[2] + fp2b[2];
        float mx = fmaxf(l0, fmaxf(l1, l2));
        float e0 = __expf(l0 - mx), e1 = __expf(l1 - mx), e2 = __expf(l2 - mx);
        float inv = 1.f / (e0 + e1 + e2);
        out[(size_t)n * 3 + 0] = e0 * inv;
        out[(size_t)n * 3 + 1] = e1 * inv;
        out[(size_t)n * 3 + 2] = e2 * inv;
    } else if (lane == 32) {
        #pragma unroll
        for (int j = 0; j < 10; ++j)
            out[(size_t)NNODE * 3 + (size_t)n * 10 + j] =
                1.f / (1.f + __expf(-(lp[j] + pd2b[j])));
    }
}

// ---------------------------------------------------------------------------
extern "C" void kernel_launch(void* const* d_in, const int* in_sizes, int n_in,
                              void* d_out, int out_size, void* d_ws, size_t ws_size,
                              hipStream_t stream) {
    const float* x    = (const float*)d_in[0];
    const int*   ei   = (const int*)  d_in[1];
    const float* W1   = (const float*)d_in[2];
    const float* b1   = (const float*)d_in[3];
    const float* W2   = (const float*)d_in[4];
    const float* b2   = (const float*)d_in[5];
    const float* W3   = (const float*)d_in[6];
    const float* b3   = (const float*)d_in[7];
    const float* in_w = (const float*)d_in[8];
    const float* in_b = (const float*)d_in[9];
    const float* outw = (const float*)d_in[10];
    const float* outb = (const float*)d_in[11];
    const float* fp1w = (const float*)d_in[12];
    const float* fp1b = (const float*)d_in[13];
    const float* fp2w = (const float*)d_in[14];
    const float* fp2b = (const float*)d_in[15];
    const float* pd1w = (const float*)d_in[16];
    const float* pd1b = (const float*)d_in[17];
    const float* pd2w = (const float*)d_in[18];
    const float* pd2b = (const float*)d_in[19];
    float* out = (float*)d_out;

    const int E = in_sizes[1] / 2;

    char* w = (char*)d_ws;
    auto alloc = [&](size_t bytes) {
        char* p = w; w += (bytes + 255) & ~(size_t)255; return p;
    };
    int*   degi   = (int*)alloc(NNODE * 4);
    int*   off    = (int*)alloc(NNODE * 4);
    int*   cursor = (int*)alloc(NNODE * 4);
    int*   csr    = (int*)alloc((size_t)E * 4);
    float* dinv   = (float*)alloc(NNODE * 4);
    float* invdeg = (float*)alloc(NNODE * 4);
    unsigned short* W1t   = (unsigned short*)alloc(256 * 128 * 2);
    unsigned short* W2t   = (unsigned short*)alloc(256 * 256 * 2);
    unsigned short* W3t   = (unsigned short*)alloc(256 * 256 * 2);
    unsigned short* in_wb = (unsigned short*)alloc(768 * 256 * 2);
    unsigned short* outwb = (unsigned short*)alloc(256 * 256 * 2);
    unsigned short* wcatb = (unsigned short*)alloc(256 * 256 * 2);
    float* bcat  = (float*)alloc(256 * 4);
    unsigned short* xb    = (unsigned short*)alloc((size_t)NNODE * DIN * 2);
    float* bufA  = (float*)alloc((size_t)NNODE * HDIM * 4);
    unsigned short* bufAb = (unsigned short*)alloc((size_t)NNODE * HDIM * 2);
    unsigned short* aggb1 = (unsigned short*)alloc((size_t)NNODE * HDIM * 2);
    unsigned short* aggb2 = (unsigned short*)alloc((size_t)NNODE * HDIM * 2);
    float* hf    = (float*)alloc((size_t)NNODE * HDIM * 4);
    unsigned short* hb    = (unsigned short*)alloc((size_t)NNODE * HDIM * 2);
    unsigned short* qh    = (unsigned short*)alloc((size_t)HEADS * NNODE * 32 * 2);
    unsigned short* kh    = (unsigned short*)alloc((size_t)HEADS * NNODE * 32 * 2);
    unsigned short* vt    = (unsigned short*)alloc((size_t)HEADS * 32 * NNODE * 2);
    unsigned short* po    = (unsigned short*)alloc((size_t)HEADS * NNODE * SPLIT * 32 * 2);
    float* pl    = (float*)alloc((size_t)HEADS * NNODE * SPLIT * 4);
    unsigned short* hfinb = (unsigned short*)alloc((size_t)NNODE * HDIM * 2);

    // CSR + prep (deg fused into prep; degi zeroed by async memset)
    hipMemsetAsync(degi, 0, NNODE * sizeof(int), stream);
    const int prep_slots = 557056 + E;
    k_prep<<<(prep_slots + 255) / 256, 256, 0, stream>>>(
        W1, W2, W3, in_w, outw, fp1w, pd1w, fp1b, pd1b, x, ei, E, degi,
        W1t, W2t, W3t, in_wb, outwb, wcatb, bcat, xb);
    k_scan_norm<<<1, 256, 0, stream>>>(degi, off, cursor, dinv, invdeg);
    k_fill<<<(E + 255) / 256, 256, 0, stream>>>(ei, cursor, csr, E);

    dim3 g256(HDIM / 32, NNODE / 64);   // (8,64)
    dim3 g768(768 / 32, NNODE / 64);    // (24,64)

    // conv1
    k_bgemm<DIN, 1, false, false><<<g256, 256, 0, stream>>>(xb, W1t, nullptr, nullptr, bufAb, nullptr, nullptr, HDIM);
    k_gather<0><<<NNODE, 256, 0, stream>>>(bufAb, csr, off, degi, dinv, invdeg, b1, nullptr, aggb1);
    // conv2
    k_bgemm<HDIM, 1, false, false><<<g256, 256, 0, stream>>>(aggb1, W2t, nullptr, nullptr, bufAb, nullptr, nullptr, HDIM);
    k_gather<0><<<NNODE, 256, 0, stream>>>(bufAb, csr, off, degi, dinv, invdeg, b2, nullptr, aggb2);
    // conv3
    k_bgemm<HDIM, 1, false, false><<<g256, 256, 0, stream>>>(aggb2, W3t, nullptr, nullptr, bufAb, nullptr, nullptr, HDIM);
    k_gather<1><<<NNODE, 256, 0, stream>>>(bufAb, csr, off, degi, dinv, invdeg, b3, hf, hb);

    // MHA: qkv GEMM (q,k head-major; V transposed), attention, fused merge+out-proj
    k_bgemm<HDIM, 2, true, false><<<g768, 256, 0, stream>>>(hb, in_wb, in_b, nullptr, qh, kh, vt, 768);
    k_attn_mfma<<<HEADS * SPLIT * (NNODE / 64), 256, 0, stream>>>(qh, kh, vt, po, pl);
    k_bgemm_merge<<<g256, 256, 0, stream>>>(po, pl, outwb, outb, hf, hfinb);

    // MLP heads
    k_bgemm<HDIM, 0, true, false><<<g256, 256, 0, stream>>>(hfinb, wcatb, bcat, nullptr, bufA, nullptr, nullptr, HDIM);
    k_heads2<<<NNODE / 4, 256, 0, stream>>>(bufA, fp2w, fp2b, pd2w, pd2b, out);
}